// Round 21
// baseline (330.869 us; speedup 1.0000x reference)
//
#include <hip/hip_runtime.h>
#include <hip/hip_bf16.h>
#include <stdint.h>

// out[b,o] = sum_{k,i} hyp[b,k]*h[b,i]*W2[k,i*256+o] + sum_i h[b,i]*b2[i*256+o] + bias[o]
// GEMM A[4096 x 131328] * B[131328 x 256], A = diag(hyp_k)*H per k-group — all FP16,
// 16x16x32 MFMA. BARRIER-FREE K-loop with TILE-PARITY wave split: 8 waves = 2 parities x
// 4 col-groups; wave (p,wn) owns cols [wn*32,+32) of tiles idx==p (mod 2). Read-set ==
// stage-set (private per-wave pipeline, no barriers). JIT fragment reads; 4 waves/SIMD
// hide ds_read->MFMA latency (VGPR under the 128 occupancy boundary).
// BM=128, BN=128; LDS = 4x16KB ring + 16KB scales = 80KB -> 2 blocks/CU = 4 waves/SIMD.
// p=0 schedule: STAGE_WAIT (stage idx+2, vmcnt(4)) -> READF -> MF4 x2  [R20-proven].
// p=1 schedule (R20 BUG FIXED): READF -> MF4(0) -> stage(idx+2) -> MF4(4) -> vmcnt(0);
//   the trailing vmcnt(0) restores the entry invariant (tile idx drained before READF) —
//   R20's vmcnt(4) left stage(idx)'s 4 loads in flight at READF(idx) => stale LDS reads.
// grid 512 = 8 K-slabs (==XCD) x 32 mt x 2 nt (nt-pair same XCD -> B L2-shared).
// ws: [0,8M) hypT fp32 [512][4096]; [9M,+2M) h f16; [12M,+67.2M) packed B tiles.

typedef _Float16 f16x8 __attribute__((ext_vector_type(8)));
typedef float    f32x4 __attribute__((ext_vector_type(4)));

#define KTILES     2052
#define TILE_BYTES 32768          // 64 k * 256 cols * 2B
#define HB_OFF     (9u*1024u*1024u)
#define BP_OFF     (12u*1024u*1024u)

// ---------------- out = bias ----------------
__global__ void k_init_out(const float* __restrict__ bias, float* __restrict__ out) {
    int idx = blockIdx.x * 256 + threadIdx.x;
    out[idx] = bias[idx & 255];
}

// ---------------- h fp32 -> f16 ----------------
__global__ void k_hcast(const float* __restrict__ h, _Float16* __restrict__ hb) {
    int i = (blockIdx.x * 256 + threadIdx.x) * 8;    // grid 512 x 256
    f32x4 a = *(const f32x4*)(h + i);
    f32x4 b = *(const f32x4*)(h + i + 4);
    f16x8 v;
    v[0] = (_Float16)a[0]; v[1] = (_Float16)a[1]; v[2] = (_Float16)a[2]; v[3] = (_Float16)a[3];
    v[4] = (_Float16)b[0]; v[5] = (_Float16)b[1]; v[6] = (_Float16)b[2]; v[7] = (_Float16)b[3];
    *(f16x8*)(hb + i) = v;
}

// ---------------- hypT[k][b] = relu(z@W1+b1)^T ----------------
__global__ void k_hypT(const float* __restrict__ z, const float* __restrict__ W1,
                       const float* __restrict__ b1, float* __restrict__ hypT) {
    int blk = blockIdx.x;
    int t   = threadIdx.x;                       // 512 threads; t == k
    __shared__ float zs[32][128];
    int b0 = blk * 32;
#pragma unroll
    for (int u = 0; u < 8; ++u) {
        int idx = u * 512 + t;
        zs[idx >> 7][idx & 127] = z[b0 * 128 + idx];
    }
    __syncthreads();
    float acc[32];
    float bk = b1[t];
#pragma unroll
    for (int b = 0; b < 32; ++b) acc[b] = bk;
    for (int c = 0; c < 128; ++c) {
        float w = W1[c * 512 + t];
#pragma unroll
        for (int b = 0; b < 32; ++b) acc[b] = fmaf(zs[b][c], w, acc[b]);
    }
    float* dst = hypT + (size_t)t * 4096 + b0;
#pragma unroll
    for (int v = 0; v < 8; ++v) {
        f32x4 o;
#pragma unroll
        for (int q = 0; q < 4; ++q) {
            float a = acc[v * 4 + q];
            o[q] = a > 0.f ? a : 0.f;
        }
        *(f32x4*)(dst + v * 4) = o;
    }
}

// ---------------- pack W2 (+b2) -> f16 transposed+swizzled tiles ----------------
// dst element (kk,o) at byte (o*128 + kk*2) ^ ((o&7)<<4); build in LDS, stream out 16B.
__global__ void k_pack(const float* __restrict__ W2, const float* __restrict__ b2,
                       _Float16* __restrict__ Bp) {
    __shared__ char tile[TILE_BYTES];
    int t   = blockIdx.x;
    int tid = threadIdx.x;        // 256
    long row0 = (long)t * 64;
    const float* src = (t < 2048) ? (W2 + row0 * 256) : (b2 + (row0 - 131072) * 256);
#pragma unroll
    for (int u = 0; u < 16; ++u) {
        int f = (u * 256 + tid) * 4;              // flat fp32 idx, coalesced
        f32x4 v = *(const f32x4*)(src + f);
        int kk = f >> 8;
        int o0 = f & 255;
#pragma unroll
        for (int j = 0; j < 4; ++j) {
            int o = o0 + j;
            int addr = (o * 128 + kk * 2) ^ ((o & 7) << 4);
            *(_Float16*)(tile + addr) = (_Float16)v[j];
        }
    }
    __syncthreads();
    char* dst = (char*)Bp + (size_t)t * TILE_BYTES;
#pragma unroll
    for (int v = 0; v < 8; ++v) {
        int off = (v * 256 + tid) * 16;           // coalesced 16B copy out
        *(f32x4*)(dst + off) = *(const f32x4*)(tile + off);
    }
}

// ---------------- main GEMM: BM=128, BN=128, parity split, 2 blocks/CU ---------------
__global__ __launch_bounds__(512, 2) void k_gemm(
        const _Float16* __restrict__ hb, const float* __restrict__ hypT,
        const _Float16* __restrict__ Bp, float* __restrict__ out) {
    __shared__ char smem[81920];   // 4 slots x 16KB @0; shyp f16 [64kk][16 l15][8 mf] @65536

    const int tid  = threadIdx.x;
    const int lane = tid & 63;
    const int wid  = tid >> 6;                 // 8 waves
    const int l15  = lane & 15, lg = lane >> 4;
    const int p    = wid >> 2;                 // tile parity this wave owns
    const int wn   = wid & 3;                  // col group: cols [wn*32,+32) (block-rel)

    const int bid  = blockIdx.x;               // 512
    const int s    = bid & 7;                  // K-slab == XCD
    const int rest = bid >> 3;
    const int nt   = rest & 1;
    const int mt   = rest >> 1;                // 0..31
    const int k0   = s * 64;
    const int row_base = mt * 128;
    const int NT   = (s == 7) ? 260 : 256;     // slab 7 owns 4 b2 tiles (idx 256..259)

    _Float16* shyp = (_Float16*)(smem + 65536);

    // ---- prologue: hyp slab -> LDS, lane-transposed [kk][l15][mf] ----
#pragma unroll
    for (int u = 0; u < 4; ++u) {
        int f  = (u * 512 + tid) * 4;          // 8192 floats
        int kk = f >> 7;
        int r  = f & 127;
        f32x4 v = *(const f32x4*)(hypT + (size_t)(k0 + kk) * 4096 + row_base + r);
#pragma unroll
        for (int q = 0; q < 4; ++q) {
            int rr = r + q;                    // rr = mf*16 + l15
            shyp[kk * 128 + (rr & 15) * 8 + (rr >> 4)] = (_Float16)v[q];
        }
    }

    auto tile_of = [&](int idx) {
        return (idx < 256) ? ((k0 + (idx & 63)) * 4 + (idx >> 6)) : (2048 + idx - 256);
    };
    // wave stages ITS OWN 4KB slice (block cols [wn*32,+32)) of its parity tiles
    auto stage = [&](int idx) {
        int t = tile_of(idx);
        const char* gsrc = (const char*)Bp + (size_t)t * TILE_BYTES + (nt << 14)
                         + wn * 4096 + lane * 16;
        char* ldst = smem + (idx & 3) * 16384 + wn * 4096;  // wave-uniform base
#pragma unroll
        for (int q = 0; q < 4; ++q)
            __builtin_amdgcn_global_load_lds(
                (const __attribute__((address_space(1))) void*)(gsrc + q * 1024),
                (__attribute__((address_space(3))) void*)(ldst + q * 1024), 16, 0, 0);
    };

    stage(p);                      // first own tile
    __syncthreads();               // scales + tile p visible (drains vmcnt)

    f32x4 acc[8][2];
#pragma unroll
    for (int i = 0; i < 8; ++i)
#pragma unroll
        for (int j = 0; j < 2; ++j)
#pragma unroll
            for (int q = 0; q < 4; ++q) acc[i][j][q] = 0.0f;

    // per-lane loop-invariant B-frag byte offsets within a slot (k-half flips bit 6)
    int boff0[2];
#pragma unroll
    for (int nf = 0; nf < 2; ++nf) {
        int col = wn * 32 + nf * 16 + l15;     // block-relative column
        boff0[nf] = (col * 128 + lg * 16) ^ ((col & 7) << 4);
    }

    f16x8 af[8][2];
#pragma unroll
    for (int mf = 0; mf < 8; ++mf)
#pragma unroll
        for (int ks = 0; ks < 2; ++ks)
            af[mf][ks] = *(const f16x8*)(hb + (size_t)(row_base + mf * 16 + l15) * 256
                                         + ks * 32 + lg * 8);

// JIT frag+scale read from slot of tile IDX (entry invariant: tile IDX drained)
#define READF(B00, B01, B10, B11, SC, IDX)                                                    \
    {                                                                                         \
      const char* _sB = smem + ((IDX) & 3) * 16384;                                           \
      B00 = *(const f16x8*)(_sB + boff0[0]);                                                  \
      B01 = *(const f16x8*)(_sB + boff0[1]);                                                  \
      B10 = *(const f16x8*)(_sB + (boff0[0] ^ 64));                                           \
      B11 = *(const f16x8*)(_sB + (boff0[1] ^ 64));                                           \
      SC  = *(const f16x8*)(shyp + ((IDX) & 63) * 128 + l15 * 8);                             \
    }

#define MF4(MF0, SC, B00, B01, B10, B11)                                                      \
    __builtin_amdgcn_s_setprio(1);                                                            \
    _Pragma("unroll")                                                                         \
    for (int mf = MF0; mf < MF0 + 4; ++mf) {                                                  \
      f16x8 _a0 = af[mf][0] * SC[mf];                                                         \
      f16x8 _a1 = af[mf][1] * SC[mf];                                                         \
      acc[mf][0] = __builtin_amdgcn_mfma_f32_16x16x32_f16(_a0, B00, acc[mf][0], 0, 0, 0);     \
      acc[mf][1] = __builtin_amdgcn_mfma_f32_16x16x32_f16(_a0, B01, acc[mf][1], 0, 0, 0);     \
      acc[mf][0] = __builtin_amdgcn_mfma_f32_16x16x32_f16(_a1, B10, acc[mf][0], 0, 0, 0);     \
      acc[mf][1] = __builtin_amdgcn_mfma_f32_16x16x32_f16(_a1, B11, acc[mf][1], 0, 0, 0);     \
    }                                                                                         \
    __builtin_amdgcn_s_setprio(0);

// p=0 step: stage(idx+2) + vmcnt(4) (drains stage(idx): invariant for READF below)
#define STAGE_WAIT(IDX)                                                                       \
    {                                                                                         \
      asm volatile("s_waitcnt lgkmcnt(0)" ::: "memory");   /* WAR: prior-step slot reads */   \
      if ((IDX) + 2 < NT) {                                                                   \
        stage((IDX) + 2);                                                                     \
        asm volatile("s_waitcnt vmcnt(4)" ::: "memory");                                      \
      } else {                                                                                \
        asm volatile("s_waitcnt vmcnt(0)" ::: "memory");                                      \
      }                                                                                       \
    }

    for (int G = 0; G < 4; ++G) {
        if (G > 0) {
#pragma unroll
            for (int mf = 0; mf < 8; ++mf)
#pragma unroll
                for (int ks = 0; ks < 2; ++ks)
                    af[mf][ks] = *(const f16x8*)(hb + (size_t)(row_base + mf * 16 + l15) * 256
                                                 + G * 64 + ks * 32 + lg * 8);
        }
        if (p == 0) {
            for (int jj = 0; jj < 64; jj += 2) {      // own tiles: even idx
                const int idx = G * 64 + jj;
                STAGE_WAIT(idx);
                f16x8 b00, b01, b10, b11, sc;
                READF(b00, b01, b10, b11, sc, idx);
                MF4(0, sc, b00, b01, b10, b11);
                MF4(4, sc, b00, b01, b10, b11);
            }
        } else {
            for (int jj = 1; jj < 64; jj += 2) {      // own tiles: odd idx; antiphase
                const int idx = G * 64 + jj;
                f16x8 b00, b01, b10, b11, sc;
                READF(b00, b01, b10, b11, sc, idx);   // entry invariant: all own loads drained
                MF4(0, sc, b00, b01, b10, b11);
                __builtin_amdgcn_sched_barrier(0);
                asm volatile("s_waitcnt lgkmcnt(0)" ::: "memory");   // WAR guard
                if (idx + 2 < NT) stage(idx + 2);
                __builtin_amdgcn_sched_barrier(0);
                MF4(4, sc, b00, b01, b10, b11);
                asm volatile("s_waitcnt vmcnt(0)" ::: "memory");     // restore invariant
            }
        }
    }

    // ---- b2 tail (slab 7 only): own tiles 256+p, 258+p; scale = 1 ----
    if (s == 7) {
        for (int m = p; m < 4; m += 2) {
            const int idx = 256 + m;
            // af for i0-group m
#pragma unroll
            for (int mf = 0; mf < 8; ++mf)
#pragma unroll
                for (int ks = 0; ks < 2; ++ks)
                    af[mf][ks] = *(const f16x8*)(hb + (size_t)(row_base + mf * 16 + l15) * 256
                                                 + m * 64 + ks * 32 + lg * 8);
            STAGE_WAIT(idx);
            const char* sB = smem + (idx & 3) * 16384;
            f16x8 b00 = *(const f16x8*)(sB + boff0[0]);
            f16x8 b01 = *(const f16x8*)(sB + boff0[1]);
            f16x8 b10 = *(const f16x8*)(sB + (boff0[0] ^ 64));
            f16x8 b11 = *(const f16x8*)(sB + (boff0[1] ^ 64));
#pragma unroll
            for (int mf = 0; mf < 8; ++mf) {
                acc[mf][0] = __builtin_amdgcn_mfma_f32_16x16x32_f16(af[mf][0], b00, acc[mf][0], 0, 0, 0);
                acc[mf][1] = __builtin_amdgcn_mfma_f32_16x16x32_f16(af[mf][0], b01, acc[mf][1], 0, 0, 0);
                acc[mf][0] = __builtin_amdgcn_mfma_f32_16x16x32_f16(af[mf][1], b10, acc[mf][0], 0, 0, 0);
                acc[mf][1] = __builtin_amdgcn_mfma_f32_16x16x32_f16(af[mf][1], b11, acc[mf][1], 0, 0, 0);
            }
        }
    }

    // ---- epilogue: atomic split-K accumulate (out pre-initialized with bias) ----
#pragma unroll
    for (int mf = 0; mf < 8; ++mf)
#pragma unroll
        for (int nf = 0; nf < 2; ++nf) {
            int col = nt * 128 + wn * 32 + nf * 16 + l15;
#pragma unroll
            for (int q = 0; q < 4; ++q) {
                int row = row_base + mf * 16 + lg * 4 + q;  // C/D: col=lane&15, row=(lane>>4)*4+q
                atomicAdd(&out[row * 256 + col], acc[mf][nf][q]);
            }
        }
}

extern "C" void kernel_launch(void* const* d_in, const int* in_sizes, int n_in,
                              void* d_out, int out_size, void* d_ws, size_t ws_size,
                              hipStream_t stream) {
    const float* h    = (const float*)d_in[0];  // [4096,256]
    const float* z    = (const float*)d_in[1];  // [4096,128]
    const float* W1   = (const float*)d_in[2];  // [128,512]
    const float* b1   = (const float*)d_in[3];  // [512]
    const float* W2   = (const float*)d_in[4];  // [512,65536]
    const float* b2   = (const float*)d_in[5];  // [65536]
    const float* bias = (const float*)d_in[6];  // [1,256]
    float* out = (float*)d_out;                 // [4096,256] fp32

    float*     hypT = (float*)d_ws;                          // 512*4096*4 = 8 MB
    _Float16*  hb   = (_Float16*)((char*)d_ws + HB_OFF);     // 2 MB f16 h
    _Float16*  Bp   = (_Float16*)((char*)d_ws + BP_OFF);     // 67.2 MB

    k_pack    <<<KTILES, 256, 0, stream>>>(W2, b2, Bp);
    k_hypT    <<<128,    512, 0, stream>>>(z, W1, b1, hypT);
    k_hcast   <<<512,    256, 0, stream>>>(h, hb);
    k_init_out<<<4096,   256, 0, stream>>>(bias, out);
    k_gemm    <<<512,    512, 0, stream>>>(hb, hypT, Bp, out);
}